// Round 10
// baseline (235.212 us; speedup 1.0000x reference)
//
#include <hip/hip_runtime.h>
#include <math.h>

#define Bq 2
#define Lq 2048
#define Eq 1024
#define Hq 16
#define Dq 64

// exp(-sqrt(d2)) = exp2(-sqrt(C2*d2)), C2 = (log2 e)^2. q2/k2 are pre-scaled
// by C2 in proj3; the -2*C2 factor is folded into the score fmaf in flash.
#define C2LOG2E 2.0813689810056077f
#define NEG2C2  -4.1627379620112154f

typedef __attribute__((ext_vector_type(8))) short bf16x8;
typedef __attribute__((ext_vector_type(4))) short bf16x4;
typedef __attribute__((ext_vector_type(4))) float f32x4;

__device__ __forceinline__ short f2bf(float f) {
    union { float f; unsigned u; } x; x.f = f;
    unsigned r = x.u + 0x7FFFu + ((x.u >> 16) & 1u);
    return (short)(r >> 16);
}
__device__ __forceinline__ float bf2f(short s) {
    union { unsigned u; float f; } x;
    x.u = ((unsigned)(unsigned short)s) << 16;
    return x.f;
}

// 8x f32 -> 8x bf16 (RNE, identical to f2bf) via 4x v_cvt_pk_bf16_f32.
__device__ __forceinline__ bf16x8 cvt8(float4 a, float4 b) {
    union { unsigned u[4]; bf16x8 v; } r;
    asm("v_cvt_pk_bf16_f32 %0, %1, %2" : "=v"(r.u[0]) : "v"(a.x), "v"(a.y));
    asm("v_cvt_pk_bf16_f32 %0, %1, %2" : "=v"(r.u[1]) : "v"(a.z), "v"(a.w));
    asm("v_cvt_pk_bf16_f32 %0, %1, %2" : "=v"(r.u[2]) : "v"(b.x), "v"(b.y));
    asm("v_cvt_pk_bf16_f32 %0, %1, %2" : "=v"(r.u[3]) : "v"(b.z), "v"(b.w));
    return r.v;
}

// XOR swizzle for [rows][64] bf16 tiles (64-short rows = 128B): spreads the
// 16B slot of row r by r&7. Bijective; preserves 8B/16B alignment. Used for
// the K tile only (V tile now has 32-short rows which are naturally
// bank-uniform; P uses stride-40 padding).
__device__ __forceinline__ int swz(int off) {
    return off ^ (((off >> 6) & 7) << 3);
}

// Zero the osum accumulator (2*1024 floats).
__global__ __launch_bounds__(256) void zero_os(float* __restrict__ os) {
    float4 zv = {0.f, 0.f, 0.f, 0.f};
    ((float4*)os)[blockIdx.x * 256 + threadIdx.x] = zv;
}

// All three projections, reading f32 inputs directly (r8-exact, measured):
// staging loads 2x float4 per pointer, converts via cvt_pk (RNE == f2bf) at
// ds_write. Block tile 128x128, BK=32, wave tile 64x64, 256 threads. Single
// barrier per K-step, LDS double-buffered (stride-40), one-step reg prefetch.
__global__ __launch_bounds__(256, 3) void proj3_kernel(const float* __restrict__ Qf,
                                                       const float* __restrict__ Kf,
                                                       const float* __restrict__ Vf,
                                                       const float* __restrict__ Wqf,
                                                       const float* __restrict__ Wkf,
                                                       const float* __restrict__ Wvf,
                                                       short* __restrict__ qb,
                                                       short* __restrict__ kb,
                                                       short* __restrict__ vT,
                                                       float* __restrict__ q2,
                                                       float* __restrict__ k2) {
    const int wave = threadIdx.x >> 6;
    const int lane = threadIdx.x & 63;
    const int l15 = lane & 15, quad = lane >> 4;
    const int pidx = blockIdx.y >> 3;
    const float* Xb = (pidx == 0) ? Qf : (pidx == 1) ? Kf : Vf;
    const float* Wb = (pidx == 0) ? Wqf : (pidx == 1) ? Wkf : Wvf;
    short* outb = (pidx == 0) ? qb : (pidx == 1) ? kb : vT;
    float* x2 = (pidx == 0) ? q2 : (pidx == 1) ? k2 : nullptr;
    const int transposed = (pidx == 2);
    const int m0 = blockIdx.x * 128;
    const int n0 = (blockIdx.y & 7) * 128;
    const int wm = wave & 1, wn = wave >> 1;

    __shared__ __align__(16) short lds_a[2 * 128 * 40];
    __shared__ __align__(16) short lds_b[2 * 128 * 40];

    const int r0 = threadIdx.x >> 2;            // rows 0..63
    const int r1 = 64 + r0;                     // rows 64..127
    const int cc = (threadIdx.x & 3) * 8;       // col chunk (elements)
    const float* gA0 = Xb + (size_t)(m0 + r0) * Eq + cc;
    const float* gA1 = Xb + (size_t)(m0 + r1) * Eq + cc;
    const float* gB0 = Wb + (size_t)(n0 + r0) * Eq + cc;
    const float* gB1 = Wb + (size_t)(n0 + r1) * Eq + cc;
    const int wa0 = r0 * 40 + cc;               // write offsets within a buffer
    const int wa1 = r1 * 40 + cc;

    f32x4 acc[4][4] = {};

    // prologue: step0 -> regs -> cvt -> buf0; step1 -> regs
    float4 a0l = *(const float4*)gA0, a0h = *(const float4*)(gA0 + 4);
    float4 a1l = *(const float4*)gA1, a1h = *(const float4*)(gA1 + 4);
    float4 b0l = *(const float4*)gB0, b0h = *(const float4*)(gB0 + 4);
    float4 b1l = *(const float4*)gB1, b1h = *(const float4*)(gB1 + 4);
    *(bf16x8*)(lds_a + wa0) = cvt8(a0l, a0h);
    *(bf16x8*)(lds_a + wa1) = cvt8(a1l, a1h);
    *(bf16x8*)(lds_b + wa0) = cvt8(b0l, b0h);
    *(bf16x8*)(lds_b + wa1) = cvt8(b1l, b1h);
    a0l = *(const float4*)(gA0 + 32); a0h = *(const float4*)(gA0 + 36);
    a1l = *(const float4*)(gA1 + 32); a1h = *(const float4*)(gA1 + 36);
    b0l = *(const float4*)(gB0 + 32); b0h = *(const float4*)(gB0 + 36);
    b1l = *(const float4*)(gB1 + 32); b1h = *(const float4*)(gB1 + 36);
    __syncthreads();

#pragma unroll 1
    for (int e0 = 0; e0 < Eq; e0 += 32) {
        const int sb = ((e0 >> 5) & 1) * 5120;   // current buffer
        const int nb = 5120 - sb;                // idle (next) buffer
        if (e0 + 32 < Eq) {
            // cvt + write prefetched step e0+32 into idle buffer (overlaps MFMA)
            *(bf16x8*)(lds_a + nb + wa0) = cvt8(a0l, a0h);
            *(bf16x8*)(lds_a + nb + wa1) = cvt8(a1l, a1h);
            *(bf16x8*)(lds_b + nb + wa0) = cvt8(b0l, b0h);
            *(bf16x8*)(lds_b + nb + wa1) = cvt8(b1l, b1h);
            if (e0 + 64 < Eq) {
                // issue f32 global loads for step e0+64 (land next iteration)
                a0l = *(const float4*)(gA0 + e0 + 64); a0h = *(const float4*)(gA0 + e0 + 68);
                a1l = *(const float4*)(gA1 + e0 + 64); a1h = *(const float4*)(gA1 + e0 + 68);
                b0l = *(const float4*)(gB0 + e0 + 64); b0h = *(const float4*)(gB0 + e0 + 68);
                b1l = *(const float4*)(gB1 + e0 + 64); b1h = *(const float4*)(gB1 + e0 + 68);
            }
        }

        bf16x8 af[4], bfr[4];
#pragma unroll
        for (int i = 0; i < 4; ++i)
            af[i] = *(const bf16x8*)(lds_a + sb + (wm * 64 + i * 16 + l15) * 40 + quad * 8);
#pragma unroll
        for (int j = 0; j < 4; ++j)
            bfr[j] = *(const bf16x8*)(lds_b + sb + (wn * 64 + j * 16 + l15) * 40 + quad * 8);
#pragma unroll
        for (int i = 0; i < 4; ++i)
#pragma unroll
            for (int j = 0; j < 4; ++j)
                acc[i][j] = __builtin_amdgcn_mfma_f32_16x16x32_bf16(af[i], bfr[j], acc[i][j], 0, 0, 0);
        __syncthreads();   // step e0+32 fully staged; reads of buf sb done
    }

    const int mw = m0 + wm * 64;
    const int nw = n0 + wn * 64;
    const int h = nw >> 6;
#pragma unroll
    for (int i = 0; i < 4; ++i) {
        float ss[4] = {0.f, 0.f, 0.f, 0.f};
#pragma unroll
        for (int r = 0; r < 4; ++r) {
            int tok = mw + i * 16 + quad * 4 + r;
            int b = tok >> 11, l = tok & 2047;
#pragma unroll
            for (int j = 0; j < 4; ++j) {
                int d = (nw + j * 16 + l15) & 63;
                short sb2 = f2bf(acc[i][j][r]);
                float sv = bf2f(sb2);
                ss[r] += sv * sv;
                size_t idx = transposed
                                 ? (((size_t)(b * Hq + h) * Dq + d) * Lq + l)
                                 : (((size_t)(b * Hq + h) * Lq + l) * Dq + d);
                outb[idx] = sb2;
            }
        }
        if (x2 != nullptr) {
#pragma unroll
            for (int r = 0; r < 4; ++r) {
#pragma unroll
                for (int off = 1; off < 16; off <<= 1) ss[r] += __shfl_xor(ss[r], off);
            }
            if (l15 == 0) {
#pragma unroll
                for (int r = 0; r < 4; ++r) {
                    int tok = mw + i * 16 + quad * 4 + r;
                    int b = tok >> 11, l = tok & 2047;
                    x2[(size_t)(b * Hq + h) * Lq + l] = ss[r] * C2LOG2E;
                }
            }
        }
    }
}

// Flash attention, scores = -||q-k||, fixed softmax max = 0.
// Same r6 loop skeleton (single barrier/tile, dbuf, one-tile-ahead staging +
// two-tile-ahead loads) but KVBLK=32: LDS = 8K (K dbuf, swizzled 64-short
// rows) + 8K (V dbuf, 32-short rows, naturally bank-uniform) + 5K (P,
// stride-40 rows, b64-write/b128-read both at wave floor) = 21504 B ->
// 7 blocks/CU = 28 waves (was 4 blocks/16 waves): occupancy is the lever.
// Per tile per wave: 2 kt QK^T (4 MFMA) + softmax over 8 keys/lane + 1 PV
// A-frag x 4 V-frags (4 MFMA). 64 tiles. Grid (32, B*H), 256 threads.
__global__ __launch_bounds__(256) void flash_kernel(const short* __restrict__ qb,
                                                    const short* __restrict__ kb,
                                                    const short* __restrict__ vT,
                                                    const float* __restrict__ q2,
                                                    const float* __restrict__ k2,
                                                    float* __restrict__ osum) {
    const int wave = threadIdx.x >> 6;
    const int lane = threadIdx.x & 63;
    const int l15 = lane & 15, quad = lane >> 4;
    const int bh = blockIdx.y;
    const int q0 = blockIdx.x * 64 + wave * 16;
    const short* qbh = qb + (size_t)bh * Lq * Dq;
    const short* kbh = kb + (size_t)bh * Lq * Dq;
    const short* vbh = vT + (size_t)bh * Dq * Lq;
    const float* q2h = q2 + (size_t)bh * Lq;
    const float* k2h = k2 + (size_t)bh * Lq;

    __shared__ __align__(16) short lds_k[2 * 32 * 64];   // K dbuf (swizzled)
    __shared__ __align__(16) short lds_v[2 * 64 * 32];   // V dbuf (linear)
    __shared__ __align__(16) short plds[4 * 16 * 40];    // P per wave, stride 40
    short* pl = plds + wave * 640;

    // Q fragment (B-operand of S^T): lane l15 = q-row, cols quad*8..+7
    const short* qp = qbh + (size_t)(q0 + l15) * Dq + quad * 8;
    bf16x8 qf0 = *(const bf16x8*)qp;
    bf16x8 qf1 = *(const bf16x8*)(qp + 32);
    const float q2l = q2h[q0 + l15];   // pre-scaled by C2LOG2E

    // staging geometry: one 16B chunk per thread per array per tile
    const int krow = threadIdx.x >> 3;          // 0..31 (K: key rows)
    const int ksc = (threadIdx.x & 7) * 8;
    const int vrow = threadIdx.x >> 2;          // 0..63 (V: d rows)
    const int vsc = (threadIdx.x & 3) * 8;
    const int wk = swz(krow * 64 + ksc);
    const int wv = vrow * 32 + vsc;

    f32x4 o[4] = {};
    float lsum = 0.f;

    // prologue: tile 0 -> regs -> buf0; tile 1 -> regs
    bf16x8 kp = *(const bf16x8*)(kbh + (size_t)krow * Dq + ksc);
    bf16x8 vp = *(const bf16x8*)(vbh + (size_t)vrow * Lq + vsc);
    *(bf16x8*)(lds_k + wk) = kp;
    *(bf16x8*)(lds_v + wv) = vp;
    kp = *(const bf16x8*)(kbh + (size_t)(32 + krow) * Dq + ksc);
    vp = *(const bf16x8*)(vbh + (size_t)vrow * Lq + 32 + vsc);
    __syncthreads();

#pragma unroll 1
    for (int it = 0; it < Lq / 32; ++it) {
        const int k0 = it * 32;
        const short* kc = lds_k + (it & 1) * 2048;
        const short* vc = lds_v + (it & 1) * 2048;
        if (it + 1 < Lq / 32) {
            // write prefetched tile it+1 into the idle buffer (overlaps compute)
            *(bf16x8*)(lds_k + ((it + 1) & 1) * 2048 + wk) = kp;
            *(bf16x8*)(lds_v + ((it + 1) & 1) * 2048 + wv) = vp;
            if (it + 2 < Lq / 32) {
                // issue global loads for tile it+2 (land next iteration)
                kp = *(const bf16x8*)(kbh + (size_t)(k0 + 64 + krow) * Dq + ksc);
                vp = *(const bf16x8*)(vbh + (size_t)vrow * Lq + k0 + 64 + vsc);
            }
        }

        // scores: S^T = K.Q^T; lane -> P[q=l15][key=kt*16+quad*4+r]
#pragma unroll
        for (int kt = 0; kt < 2; ++kt) {
            bf16x8 kf0 = *(const bf16x8*)(kc + swz((kt * 16 + l15) * 64 + quad * 8));
            bf16x8 kf1 = *(const bf16x8*)(kc + swz((kt * 16 + l15) * 64 + 32 + quad * 8));
            f32x4 st = {0.f, 0.f, 0.f, 0.f};
            st = __builtin_amdgcn_mfma_f32_16x16x32_bf16(kf0, qf0, st, 0, 0, 0);
            st = __builtin_amdgcn_mfma_f32_16x16x32_bf16(kf1, qf1, st, 0, 0, 0);
            float4 k2v = *(const float4*)(k2h + k0 + kt * 16 + quad * 4);  // pre-scaled
            float pv[4];
#pragma unroll
            for (int r = 0; r < 4; ++r) {
                // d2' = C2*(q2+k2-2qk): fold -2*C2 into the fmaf constant
                float d2 = fmaxf(fmaf(st[r], NEG2C2, q2l + ((const float*)&k2v)[r]), 0.f);
                float ys = __builtin_amdgcn_sqrtf(d2);
                pv[r] = __builtin_amdgcn_exp2f(-ys);   // neg folds into v_exp src mod
            }
            lsum += (pv[0] + pv[1]) + (pv[2] + pv[3]);
            // pack 4 bf16 with 2x v_cvt_pk_bf16_f32 (no builtin on gfx950)
            unsigned plo, phi;
            asm("v_cvt_pk_bf16_f32 %0, %1, %2" : "=v"(plo) : "v"(pv[0]), "v"(pv[1]));
            asm("v_cvt_pk_bf16_f32 %0, %1, %2" : "=v"(phi) : "v"(pv[2]), "v"(pv[3]));
            uint2 pw; pw.x = plo; pw.y = phi;
            // packed b64 write: row q=l15 (stride 40), cols kt*16+quad*4..+3
            *(uint2*)(pl + l15 * 40 + kt * 16 + quad * 4) = pw;
        }
        // PV: P back as one K=32 A-fragment (b128), V as B-fragments (b128)
        {
            bf16x8 pa = *(const bf16x8*)(pl + l15 * 40 + quad * 8);
#pragma unroll
            for (int f = 0; f < 4; ++f) {
                bf16x8 vf = *(const bf16x8*)(vc + (f * 16 + l15) * 32 + quad * 8);
                o[f] = __builtin_amdgcn_mfma_f32_16x16x32_bf16(pa, vf, o[f], 0, 0, 0);
            }
        }
        __syncthreads();   // tile it+1 fully staged; reads of buf (it&1) done
    }

    // lsum: lane holds partial for q-row l15 (its quad's keys); reduce over quads
    lsum += __shfl_xor(lsum, 16);
    lsum += __shfl_xor(lsum, 32);
    // O lane layout: row=quad*4+r = q-row, col=l15 = d-within-16
    float lq[4];
#pragma unroll
    for (int r = 0; r < 4; ++r) lq[r] = __shfl(lsum, quad * 4 + r);
#pragma unroll
    for (int f = 0; f < 4; ++f) {
        float cs = o[f][0] / lq[0] + o[f][1] / lq[1] +
                   o[f][2] / lq[2] + o[f][3] / lq[3];
        cs += __shfl_xor(cs, 16);
        cs += __shfl_xor(cs, 32);
        if (quad == 0) atomicAdd(&osum[(size_t)bh * Dq + f * 16 + l15], cs);
    }
}

// out[b,j] = sum_e osum[b,e] * Wo[j,e]; one wave per output element
__global__ __launch_bounds__(256) void outproj_kernel(const float* __restrict__ osum,
                                                      const float* __restrict__ Wo,
                                                      float* __restrict__ out) {
    int idx = blockIdx.x * 4 + (threadIdx.x >> 6);
    int lane = threadIdx.x & 63;
    int b = idx >> 10, j = idx & 1023;
    const float* o = osum + (size_t)b * Eq;
    const float* w = Wo + (size_t)j * Eq;
    float4 s4 = {0.f, 0.f, 0.f, 0.f};
    for (int e = lane * 4; e < Eq; e += 256) {
        float4 ov = *(const float4*)(o + e);
        float4 wv = *(const float4*)(w + e);
        s4.x += ov.x * wv.x; s4.y += ov.y * wv.y;
        s4.z += ov.z * wv.z; s4.w += ov.w * wv.w;
    }
    float s = s4.x + s4.y + s4.z + s4.w;
#pragma unroll
    for (int off = 1; off < 64; off <<= 1) s += __shfl_xor(s, off);
    if (lane == 0) out[idx] = s;
}

extern "C" void kernel_launch(void* const* d_in, const int* in_sizes, int n_in,
                              void* d_out, int out_size, void* d_ws, size_t ws_size,
                              hipStream_t stream) {
    const float* Q  = (const float*)d_in[0];
    const float* K  = (const float*)d_in[1];
    const float* V  = (const float*)d_in[2];
    const float* Wq = (const float*)d_in[3];
    const float* Wk = (const float*)d_in[4];
    const float* Wv = (const float*)d_in[5];
    const float* Wo = (const float*)d_in[6];
    float* out = (float*)d_out;

    char* ws = (char*)d_ws;
    // [0,8M) qb | [8M,16M) kb | [16M,24M) vT | q2 | k2 | osum
    short* qb = (short*)ws;
    short* kb = (short*)(ws + (size_t)(8 << 20));
    short* vT = (short*)(ws + (size_t)(16 << 20));
    float* q2 = (float*)(ws + (size_t)(24 << 20));
    float* k2 = (float*)(ws + (size_t)(24 << 20) + (256 << 10));
    float* os = (float*)(ws + (size_t)(24 << 20) + (512 << 10));

    zero_os<<<2, 256, 0, stream>>>(os);
    proj3_kernel<<<dim3(32, 24), 256, 0, stream>>>(Q, K, V, Wq, Wk, Wv, qb, kb, vT, q2, k2);
    flash_kernel<<<dim3(32, 32), 256, 0, stream>>>(qb, kb, vT, q2, k2, os);
    outproj_kernel<<<512, 256, 0, stream>>>(os, Wo, out);
}

// Round 11
// 223.944 us; speedup vs baseline: 1.0503x; 1.0503x over previous
//
#include <hip/hip_runtime.h>
#include <math.h>

#define Bq 2
#define Lq 2048
#define Eq 1024
#define Hq 16
#define Dq 64

// exp(-sqrt(d2)) = exp2(-sqrt(C2*d2)), C2 = (log2 e)^2. q2/k2 are pre-scaled
// by C2 in proj3; the -2*C2 factor is folded into the score fmaf in flash.
#define C2LOG2E 2.0813689810056077f
#define NEG2C2  -4.1627379620112154f

typedef __attribute__((ext_vector_type(8))) short bf16x8;
typedef __attribute__((ext_vector_type(4))) short bf16x4;
typedef __attribute__((ext_vector_type(4))) float f32x4;

__device__ __forceinline__ short f2bf(float f) {
    union { float f; unsigned u; } x; x.f = f;
    unsigned r = x.u + 0x7FFFu + ((x.u >> 16) & 1u);
    return (short)(r >> 16);
}
__device__ __forceinline__ float bf2f(short s) {
    union { unsigned u; float f; } x;
    x.u = ((unsigned)(unsigned short)s) << 16;
    return x.f;
}

// 8x f32 -> 8x bf16 (RNE, identical to f2bf) via 4x v_cvt_pk_bf16_f32.
__device__ __forceinline__ bf16x8 cvt8(float4 a, float4 b) {
    union { unsigned u[4]; bf16x8 v; } r;
    asm("v_cvt_pk_bf16_f32 %0, %1, %2" : "=v"(r.u[0]) : "v"(a.x), "v"(a.y));
    asm("v_cvt_pk_bf16_f32 %0, %1, %2" : "=v"(r.u[1]) : "v"(a.z), "v"(a.w));
    asm("v_cvt_pk_bf16_f32 %0, %1, %2" : "=v"(r.u[2]) : "v"(b.x), "v"(b.y));
    asm("v_cvt_pk_bf16_f32 %0, %1, %2" : "=v"(r.u[3]) : "v"(b.z), "v"(b.w));
    return r.v;
}

// XOR swizzle for [rows][64] bf16 tiles (64-short rows = 128B): spreads the
// 16B slot of row r by r&7. Bijective; preserves 8B/16B alignment (touches
// only short-address bits 3..5). (r4-verified on the P/K/V tiles.)
__device__ __forceinline__ int swz(int off) {
    return off ^ (((off >> 6) & 7) << 3);
}

// Zero the osum accumulator (2*1024 floats).
__global__ __launch_bounds__(256) void zero_os(float* __restrict__ os) {
    float4 zv = {0.f, 0.f, 0.f, 0.f};
    ((float4*)os)[blockIdx.x * 256 + threadIdx.x] = zv;
}

// All three projections, reading f32 inputs directly (r8-exact, measured):
// staging loads 2x float4 per pointer, converts via cvt_pk (RNE == f2bf) at
// ds_write. Block tile 128x128, BK=32, wave tile 64x64, 256 threads. Single
// barrier per K-step, LDS double-buffered (stride-40), one-step reg prefetch.
__global__ __launch_bounds__(256, 3) void proj3_kernel(const float* __restrict__ Qf,
                                                       const float* __restrict__ Kf,
                                                       const float* __restrict__ Vf,
                                                       const float* __restrict__ Wqf,
                                                       const float* __restrict__ Wkf,
                                                       const float* __restrict__ Wvf,
                                                       short* __restrict__ qb,
                                                       short* __restrict__ kb,
                                                       short* __restrict__ vT,
                                                       float* __restrict__ q2,
                                                       float* __restrict__ k2) {
    const int wave = threadIdx.x >> 6;
    const int lane = threadIdx.x & 63;
    const int l15 = lane & 15, quad = lane >> 4;
    const int pidx = blockIdx.y >> 3;
    const float* Xb = (pidx == 0) ? Qf : (pidx == 1) ? Kf : Vf;
    const float* Wb = (pidx == 0) ? Wqf : (pidx == 1) ? Wkf : Wvf;
    short* outb = (pidx == 0) ? qb : (pidx == 1) ? kb : vT;
    float* x2 = (pidx == 0) ? q2 : (pidx == 1) ? k2 : nullptr;
    const int transposed = (pidx == 2);
    const int m0 = blockIdx.x * 128;
    const int n0 = (blockIdx.y & 7) * 128;
    const int wm = wave & 1, wn = wave >> 1;

    __shared__ __align__(16) short lds_a[2 * 128 * 40];
    __shared__ __align__(16) short lds_b[2 * 128 * 40];

    const int r0 = threadIdx.x >> 2;            // rows 0..63
    const int r1 = 64 + r0;                     // rows 64..127
    const int cc = (threadIdx.x & 3) * 8;       // col chunk (elements)
    const float* gA0 = Xb + (size_t)(m0 + r0) * Eq + cc;
    const float* gA1 = Xb + (size_t)(m0 + r1) * Eq + cc;
    const float* gB0 = Wb + (size_t)(n0 + r0) * Eq + cc;
    const float* gB1 = Wb + (size_t)(n0 + r1) * Eq + cc;
    const int wa0 = r0 * 40 + cc;               // write offsets within a buffer
    const int wa1 = r1 * 40 + cc;

    f32x4 acc[4][4] = {};

    // prologue: step0 -> regs -> cvt -> buf0; step1 -> regs
    float4 a0l = *(const float4*)gA0, a0h = *(const float4*)(gA0 + 4);
    float4 a1l = *(const float4*)gA1, a1h = *(const float4*)(gA1 + 4);
    float4 b0l = *(const float4*)gB0, b0h = *(const float4*)(gB0 + 4);
    float4 b1l = *(const float4*)gB1, b1h = *(const float4*)(gB1 + 4);
    *(bf16x8*)(lds_a + wa0) = cvt8(a0l, a0h);
    *(bf16x8*)(lds_a + wa1) = cvt8(a1l, a1h);
    *(bf16x8*)(lds_b + wa0) = cvt8(b0l, b0h);
    *(bf16x8*)(lds_b + wa1) = cvt8(b1l, b1h);
    a0l = *(const float4*)(gA0 + 32); a0h = *(const float4*)(gA0 + 36);
    a1l = *(const float4*)(gA1 + 32); a1h = *(const float4*)(gA1 + 36);
    b0l = *(const float4*)(gB0 + 32); b0h = *(const float4*)(gB0 + 36);
    b1l = *(const float4*)(gB1 + 32); b1h = *(const float4*)(gB1 + 36);
    __syncthreads();

#pragma unroll 1
    for (int e0 = 0; e0 < Eq; e0 += 32) {
        const int sb = ((e0 >> 5) & 1) * 5120;   // current buffer
        const int nb = 5120 - sb;                // idle (next) buffer
        if (e0 + 32 < Eq) {
            // cvt + write prefetched step e0+32 into idle buffer (overlaps MFMA)
            *(bf16x8*)(lds_a + nb + wa0) = cvt8(a0l, a0h);
            *(bf16x8*)(lds_a + nb + wa1) = cvt8(a1l, a1h);
            *(bf16x8*)(lds_b + nb + wa0) = cvt8(b0l, b0h);
            *(bf16x8*)(lds_b + nb + wa1) = cvt8(b1l, b1h);
            if (e0 + 64 < Eq) {
                // issue f32 global loads for step e0+64 (land next iteration)
                a0l = *(const float4*)(gA0 + e0 + 64); a0h = *(const float4*)(gA0 + e0 + 68);
                a1l = *(const float4*)(gA1 + e0 + 64); a1h = *(const float4*)(gA1 + e0 + 68);
                b0l = *(const float4*)(gB0 + e0 + 64); b0h = *(const float4*)(gB0 + e0 + 68);
                b1l = *(const float4*)(gB1 + e0 + 64); b1h = *(const float4*)(gB1 + e0 + 68);
            }
        }

        bf16x8 af[4], bfr[4];
#pragma unroll
        for (int i = 0; i < 4; ++i)
            af[i] = *(const bf16x8*)(lds_a + sb + (wm * 64 + i * 16 + l15) * 40 + quad * 8);
#pragma unroll
        for (int j = 0; j < 4; ++j)
            bfr[j] = *(const bf16x8*)(lds_b + sb + (wn * 64 + j * 16 + l15) * 40 + quad * 8);
#pragma unroll
        for (int i = 0; i < 4; ++i)
#pragma unroll
            for (int j = 0; j < 4; ++j)
                acc[i][j] = __builtin_amdgcn_mfma_f32_16x16x32_bf16(af[i], bfr[j], acc[i][j], 0, 0, 0);
        __syncthreads();   // step e0+32 fully staged; reads of buf sb done
    }

    const int mw = m0 + wm * 64;
    const int nw = n0 + wn * 64;
    const int h = nw >> 6;
#pragma unroll
    for (int i = 0; i < 4; ++i) {
        float ss[4] = {0.f, 0.f, 0.f, 0.f};
#pragma unroll
        for (int r = 0; r < 4; ++r) {
            int tok = mw + i * 16 + quad * 4 + r;
            int b = tok >> 11, l = tok & 2047;
#pragma unroll
            for (int j = 0; j < 4; ++j) {
                int d = (nw + j * 16 + l15) & 63;
                short sb2 = f2bf(acc[i][j][r]);
                float sv = bf2f(sb2);
                ss[r] += sv * sv;
                size_t idx = transposed
                                 ? (((size_t)(b * Hq + h) * Dq + d) * Lq + l)
                                 : (((size_t)(b * Hq + h) * Lq + l) * Dq + d);
                outb[idx] = sb2;
            }
        }
        if (x2 != nullptr) {
#pragma unroll
            for (int r = 0; r < 4; ++r) {
#pragma unroll
                for (int off = 1; off < 16; off <<= 1) ss[r] += __shfl_xor(ss[r], off);
            }
            if (l15 == 0) {
#pragma unroll
                for (int r = 0; r < 4; ++r) {
                    int tok = mw + i * 16 + quad * 4 + r;
                    int b = tok >> 11, l = tok & 2047;
                    x2[(size_t)(b * Hq + h) * Lq + l] = ss[r] * C2LOG2E;
                }
            }
        }
    }
}

// Flash attention, scores = -||q-k||, fixed softmax max = 0.  (r6-exact loop,
// measured 80.8us.) S^T = K.Q^T (swapped operands): lane holds
// P[q=l15][keys quad*4..+3]. Single barrier per 64-key tile; K/V double-
// buffered in LDS (XOR-swizzled stride-64 tiles: 16K+16K+8K = 40960B =
// 4 blocks/CU). Iter i: ds_write prefetched tile i+1 -> idle buffer, issue
// global loads for tile i+2, compute tile i, ONE barrier.
// THIS ROUND: bijective XCD-aware block remap (1024 = 8 XCD x 128): each
// XCD's blocks cover exactly 4 bh -> K/V working set 2MB < 4MB L2 per XCD.
// Targets the measured 3x K/V over-fetch (FETCH 70.8MB vs ~24MB ideal).
// Grid (32, B*H) = 1024 blocks, 256 threads.
__global__ __launch_bounds__(256) void flash_kernel(const short* __restrict__ qb,
                                                    const short* __restrict__ kb,
                                                    const short* __restrict__ vT,
                                                    const float* __restrict__ q2,
                                                    const float* __restrict__ k2,
                                                    float* __restrict__ osum) {
    const int wave = threadIdx.x >> 6;
    const int lane = threadIdx.x & 63;
    const int l15 = lane & 15, quad = lane >> 4;

    // XCD-aware remap (HW assigns linear id round-robin over 8 XCDs):
    // XCD x gets logical blocks for bh in {4x..4x+3} only.
    const int lid = blockIdx.y * gridDim.x + blockIdx.x;
    const int xcd = lid & 7, idx = lid >> 3;
    const int bh = xcd * 4 + (idx >> 5);
    const int bx = idx & 31;
    const int q0 = bx * 64 + wave * 16;

    const short* qbh = qb + (size_t)bh * Lq * Dq;
    const short* kbh = kb + (size_t)bh * Lq * Dq;
    const short* vbh = vT + (size_t)bh * Dq * Lq;
    const float* q2h = q2 + (size_t)bh * Lq;
    const float* k2h = k2 + (size_t)bh * Lq;

    __shared__ __align__(16) short lds_k[2 * 64 * 64];   // K double buffer
    __shared__ __align__(16) short lds_v[2 * 64 * 64];   // V double buffer
    __shared__ __align__(16) short plds[4 * 16 * 64];    // P per wave (swizzled)
    short* pl = plds + wave * 1024;

    // Q fragment (B-operand of S^T): lane l15 = q-row, cols quad*8..+7
    const short* qp = qbh + (size_t)(q0 + l15) * Dq + quad * 8;
    bf16x8 qf0 = *(const bf16x8*)qp;
    bf16x8 qf1 = *(const bf16x8*)(qp + 32);
    const float q2l = q2h[q0 + l15];   // pre-scaled by C2LOG2E

    // staging geometry: thread t covers 16B chunks t and t+256 of each 8KB tile
    const int row0 = threadIdx.x >> 3;
    const int row1 = 32 + row0;
    const int sc = (threadIdx.x & 7) * 8;
    const int w0 = swz(row0 * 64 + sc);
    const int w1 = swz(row1 * 64 + sc);

    f32x4 o[4] = {};
    float lsum = 0.f;

    // prologue: tile 0 -> regs -> buf0; tile 1 -> regs
    bf16x8 kp0 = *(const bf16x8*)(kbh + (size_t)row0 * Dq + sc);
    bf16x8 kp1 = *(const bf16x8*)(kbh + (size_t)row1 * Dq + sc);
    bf16x8 vp0 = *(const bf16x8*)(vbh + (size_t)row0 * Lq + sc);
    bf16x8 vp1 = *(const bf16x8*)(vbh + (size_t)row1 * Lq + sc);
    *(bf16x8*)(lds_k + w0) = kp0; *(bf16x8*)(lds_k + w1) = kp1;
    *(bf16x8*)(lds_v + w0) = vp0; *(bf16x8*)(lds_v + w1) = vp1;
    kp0 = *(const bf16x8*)(kbh + (size_t)(64 + row0) * Dq + sc);
    kp1 = *(const bf16x8*)(kbh + (size_t)(64 + row1) * Dq + sc);
    vp0 = *(const bf16x8*)(vbh + (size_t)row0 * Lq + 64 + sc);
    vp1 = *(const bf16x8*)(vbh + (size_t)row1 * Lq + 64 + sc);
    __syncthreads();

#pragma unroll 1
    for (int it = 0; it < Lq / 64; ++it) {
        const int k0 = it * 64;
        const short* kc = lds_k + (it & 1) * 4096;
        const short* vc = lds_v + (it & 1) * 4096;
        if (it + 1 < Lq / 64) {
            // write prefetched tile it+1 into the idle buffer (overlaps compute)
            short* kn = lds_k + ((it + 1) & 1) * 4096;
            short* vn = lds_v + ((it + 1) & 1) * 4096;
            *(bf16x8*)(kn + w0) = kp0; *(bf16x8*)(kn + w1) = kp1;
            *(bf16x8*)(vn + w0) = vp0; *(bf16x8*)(vn + w1) = vp1;
            if (it + 2 < Lq / 64) {
                // issue global loads for tile it+2 (land next iteration)
                const short* ks = kbh + (size_t)(k0 + 128) * Dq;
                kp0 = *(const bf16x8*)(ks + (size_t)row0 * Dq + sc);
                kp1 = *(const bf16x8*)(ks + (size_t)row1 * Dq + sc);
                vp0 = *(const bf16x8*)(vbh + (size_t)row0 * Lq + k0 + 128 + sc);
                vp1 = *(const bf16x8*)(vbh + (size_t)row1 * Lq + k0 + 128 + sc);
            }
        }

        // scores: S^T = K.Q^T; lane -> P[q=l15][key=kt*16+quad*4+r]
#pragma unroll
        for (int kt = 0; kt < 4; ++kt) {
            bf16x8 kf0 = *(const bf16x8*)(kc + swz((kt * 16 + l15) * 64 + quad * 8));
            bf16x8 kf1 = *(const bf16x8*)(kc + swz((kt * 16 + l15) * 64 + 32 + quad * 8));
            f32x4 st = {0.f, 0.f, 0.f, 0.f};
            st = __builtin_amdgcn_mfma_f32_16x16x32_bf16(kf0, qf0, st, 0, 0, 0);
            st = __builtin_amdgcn_mfma_f32_16x16x32_bf16(kf1, qf1, st, 0, 0, 0);
            float4 k2v = *(const float4*)(k2h + k0 + kt * 16 + quad * 4);  // pre-scaled
            float pv[4];
#pragma unroll
            for (int r = 0; r < 4; ++r) {
                // d2' = C2*(q2+k2-2qk): fold -2*C2 into the fmaf constant
                float d2 = fmaxf(fmaf(st[r], NEG2C2, q2l + ((const float*)&k2v)[r]), 0.f);
                float ys = __builtin_amdgcn_sqrtf(d2);
                pv[r] = __builtin_amdgcn_exp2f(-ys);   // neg folds into v_exp src mod
            }
            lsum += (pv[0] + pv[1]) + (pv[2] + pv[3]);
            // pack 4 bf16 with 2x v_cvt_pk_bf16_f32 (no builtin on gfx950)
            unsigned plo, phi;
            asm("v_cvt_pk_bf16_f32 %0, %1, %2" : "=v"(plo) : "v"(pv[0]), "v"(pv[1]));
            asm("v_cvt_pk_bf16_f32 %0, %1, %2" : "=v"(phi) : "v"(pv[2]), "v"(pv[3]));
            uint2 pw; pw.x = plo; pw.y = phi;
            // packed b64 write: row q=l15, cols kt*16+quad*4..+3
            *(uint2*)(pl + swz(l15 * 64 + kt * 16 + quad * 4)) = pw;
        }
        // PV: P back as K=32 A-fragment (b128), V as B-fragment (b128)
#pragma unroll
        for (int kc2 = 0; kc2 < 2; ++kc2) {
            bf16x8 pa = *(const bf16x8*)(pl + swz(l15 * 64 + kc2 * 32 + quad * 8));
#pragma unroll
            for (int f = 0; f < 4; ++f) {
                bf16x8 vf = *(const bf16x8*)(vc + swz((f * 16 + l15) * 64 + kc2 * 32 + quad * 8));
                o[f] = __builtin_amdgcn_mfma_f32_16x16x32_bf16(pa, vf, o[f], 0, 0, 0);
            }
        }
        __syncthreads();   // tile it+1 fully staged; reads of buf (it&1) done
    }

    // lsum: lane holds partial for q-row l15 (its quad's keys); reduce over quads
    lsum += __shfl_xor(lsum, 16);
    lsum += __shfl_xor(lsum, 32);
    // O lane layout: row=quad*4+r = q-row, col=l15 = d-within-16
    float lq[4];
#pragma unroll
    for (int r = 0; r < 4; ++r) lq[r] = __shfl(lsum, quad * 4 + r);
#pragma unroll
    for (int f = 0; f < 4; ++f) {
        float cs = o[f][0] / lq[0] + o[f][1] / lq[1] +
                   o[f][2] / lq[2] + o[f][3] / lq[3];
        cs += __shfl_xor(cs, 16);
        cs += __shfl_xor(cs, 32);
        if (quad == 0) atomicAdd(&osum[(size_t)bh * Dq + f * 16 + l15], cs);
    }
}

// out[b,j] = sum_e osum[b,e] * Wo[j,e]; one wave per output element
__global__ __launch_bounds__(256) void outproj_kernel(const float* __restrict__ osum,
                                                      const float* __restrict__ Wo,
                                                      float* __restrict__ out) {
    int idx = blockIdx.x * 4 + (threadIdx.x >> 6);
    int lane = threadIdx.x & 63;
    int b = idx >> 10, j = idx & 1023;
    const float* o = osum + (size_t)b * Eq;
    const float* w = Wo + (size_t)j * Eq;
    float4 s4 = {0.f, 0.f, 0.f, 0.f};
    for (int e = lane * 4; e < Eq; e += 256) {
        float4 ov = *(const float4*)(o + e);
        float4 wv = *(const float4*)(w + e);
        s4.x += ov.x * wv.x; s4.y += ov.y * wv.y;
        s4.z += ov.z * wv.z; s4.w += ov.w * wv.w;
    }
    float s = s4.x + s4.y + s4.z + s4.w;
#pragma unroll
    for (int off = 1; off < 64; off <<= 1) s += __shfl_xor(s, off);
    if (lane == 0) out[idx] = s;
}

extern "C" void kernel_launch(void* const* d_in, const int* in_sizes, int n_in,
                              void* d_out, int out_size, void* d_ws, size_t ws_size,
                              hipStream_t stream) {
    const float* Q  = (const float*)d_in[0];
    const float* K  = (const float*)d_in[1];
    const float* V  = (const float*)d_in[2];
    const float* Wq = (const float*)d_in[3];
    const float* Wk = (const float*)d_in[4];
    const float* Wv = (const float*)d_in[5];
    const float* Wo = (const float*)d_in[6];
    float* out = (float*)d_out;

    char* ws = (char*)d_ws;
    // [0,8M) qb | [8M,16M) kb | [16M,24M) vT | q2 | k2 | osum
    short* qb = (short*)ws;
    short* kb = (short*)(ws + (size_t)(8 << 20));
    short* vT = (short*)(ws + (size_t)(16 << 20));
    float* q2 = (float*)(ws + (size_t)(24 << 20));
    float* k2 = (float*)(ws + (size_t)(24 << 20) + (256 << 10));
    float* os = (float*)(ws + (size_t)(24 << 20) + (512 << 10));

    zero_os<<<2, 256, 0, stream>>>(os);
    proj3_kernel<<<dim3(32, 24), 256, 0, stream>>>(Q, K, V, Wq, Wk, Wv, qb, kb, vT, q2, k2);
    flash_kernel<<<dim3(32, 32), 256, 0, stream>>>(qb, kb, vT, q2, k2, os);
    outproj_kernel<<<512, 256, 0, stream>>>(os, Wo, out);
}

// Round 12
// 222.594 us; speedup vs baseline: 1.0567x; 1.0061x over previous
//
#include <hip/hip_runtime.h>
#include <math.h>

#define Bq 2
#define Lq 2048
#define Eq 1024
#define Hq 16
#define Dq 64

// exp(-sqrt(d2)) = exp2(-sqrt(C2*d2)), C2 = (log2 e)^2. q2/k2 are pre-scaled
// by C2 in proj3; the -2*C2 factor is folded into the score fmaf in flash.
#define C2LOG2E 2.0813689810056077f
#define NEG2C2  -4.1627379620112154f

typedef __attribute__((ext_vector_type(8))) short bf16x8;
typedef __attribute__((ext_vector_type(4))) short bf16x4;
typedef __attribute__((ext_vector_type(4))) float f32x4;

__device__ __forceinline__ short f2bf(float f) {
    union { float f; unsigned u; } x; x.f = f;
    unsigned r = x.u + 0x7FFFu + ((x.u >> 16) & 1u);
    return (short)(r >> 16);
}
__device__ __forceinline__ float bf2f(short s) {
    union { unsigned u; float f; } x;
    x.u = ((unsigned)(unsigned short)s) << 16;
    return x.f;
}

// XOR swizzle for [rows][64] bf16 tiles (64-short rows = 128B): spreads the
// 16B slot of row r by r&7. Bijective; preserves 8B/16B alignment (touches
// only short-address bits 3..5). (r4-verified on the P/K/V tiles.)
__device__ __forceinline__ int swz(int off) {
    return off ^ (((off >> 6) & 7) << 3);
}

// Cast Q,K,V (4096x1024 f32) and Wq,Wk,Wv (1024x1024 f32) to bf16, laid out
// consecutively in `out`: [Xq | Xk | Xv | Wqb | Wkb | Wvb]. Tail blocks zero `os`.
__global__ __launch_bounds__(256) void cast_all(const float* __restrict__ Q,
                                                const float* __restrict__ K,
                                                const float* __restrict__ V,
                                                const float* __restrict__ Wq,
                                                const float* __restrict__ Wk,
                                                const float* __restrict__ Wv,
                                                short* __restrict__ out,
                                                float* __restrict__ os) {
    const size_t NX = (size_t)4096 * 1024 / 4;  // float4 count per X
    const size_t NW = (size_t)1024 * 1024 / 4;  // float4 count per W
    const size_t TOT = 3 * NX + 3 * NW;
    size_t id = (size_t)blockIdx.x * 256 + threadIdx.x;
    if (id >= TOT) {
        size_t z = id - TOT;
        if (z < (size_t)(Bq * Eq / 4)) {
            float4 zv = {0.f, 0.f, 0.f, 0.f};
            ((float4*)os)[z] = zv;
        }
        return;
    }
    const float* src; size_t off;
    if (id < NX)              { src = Q;  off = id; }
    else if (id < 2 * NX)     { src = K;  off = id - NX; }
    else if (id < 3 * NX)     { src = V;  off = id - 2 * NX; }
    else if (id < 3 * NX + NW)     { src = Wq; off = id - 3 * NX; }
    else if (id < 3 * NX + 2 * NW) { src = Wk; off = id - 3 * NX - NW; }
    else                           { src = Wv; off = id - 3 * NX - 2 * NW; }
    float4 v = ((const float4*)src)[off];
    bf16x4 s;
    s[0] = f2bf(v.x); s[1] = f2bf(v.y); s[2] = f2bf(v.z); s[3] = f2bf(v.w);
    ((bf16x4*)out)[id] = s;
}

// All three projections. Block tile 128x128, BK=32, wave tile 64x64.
// Single barrier per K-step: A/B tiles double-buffered in LDS (stride-40
// padding). Iter i: ds_write prefetched step i+1 regs -> idle buffer, issue
// global loads for step i+2, ds_read+MFMA step i, ONE barrier.
// LDS 2*(128*40)*2*2B = 40960B. (Measured-best configuration.)
__global__ __launch_bounds__(256) void proj3_kernel(const short* __restrict__ castb,
                                                    short* __restrict__ qb,
                                                    short* __restrict__ kb,
                                                    short* __restrict__ vT,
                                                    float* __restrict__ q2,
                                                    float* __restrict__ k2) {
    const int wave = threadIdx.x >> 6;
    const int lane = threadIdx.x & 63;
    const int l15 = lane & 15, quad = lane >> 4;
    const int pidx = blockIdx.y >> 3;
    const short* Xb = castb + (size_t)pidx * 4096 * 1024;
    const short* Wb = castb + (size_t)3 * 4096 * 1024 + (size_t)pidx * 1024 * 1024;
    short* outb = (pidx == 0) ? qb : (pidx == 1) ? kb : vT;
    float* x2 = (pidx == 0) ? q2 : (pidx == 1) ? k2 : nullptr;
    const int transposed = (pidx == 2);
    const int m0 = blockIdx.x * 128;
    const int n0 = (blockIdx.y & 7) * 128;
    const int wm = wave & 1, wn = wave >> 1;

    __shared__ __align__(16) short lds_a[2 * 128 * 40];
    __shared__ __align__(16) short lds_b[2 * 128 * 40];

    const int r0 = threadIdx.x >> 2;            // rows 0..63
    const int r1 = 64 + r0;                     // rows 64..127
    const int cc = (threadIdx.x & 3) * 8;       // col chunk (shorts)
    const short* gA0 = Xb + (size_t)(m0 + r0) * Eq + cc;
    const short* gA1 = Xb + (size_t)(m0 + r1) * Eq + cc;
    const short* gB0 = Wb + (size_t)(n0 + r0) * Eq + cc;
    const short* gB1 = Wb + (size_t)(n0 + r1) * Eq + cc;
    const int wa0 = r0 * 40 + cc;               // write offsets within a buffer
    const int wa1 = r1 * 40 + cc;

    f32x4 acc[4][4] = {};

    // prologue: step0 -> regs -> buf0; step1 -> regs
    bf16x8 pa0 = *(const bf16x8*)gA0;
    bf16x8 pa1 = *(const bf16x8*)gA1;
    bf16x8 pb0 = *(const bf16x8*)gB0;
    bf16x8 pb1 = *(const bf16x8*)gB1;
    *(bf16x8*)(lds_a + wa0) = pa0; *(bf16x8*)(lds_a + wa1) = pa1;
    *(bf16x8*)(lds_b + wa0) = pb0; *(bf16x8*)(lds_b + wa1) = pb1;
    pa0 = *(const bf16x8*)(gA0 + 32);
    pa1 = *(const bf16x8*)(gA1 + 32);
    pb0 = *(const bf16x8*)(gB0 + 32);
    pb1 = *(const bf16x8*)(gB1 + 32);
    __syncthreads();

#pragma unroll 1
    for (int e0 = 0; e0 < Eq; e0 += 32) {
        const int sb = ((e0 >> 5) & 1) * 5120;   // current buffer
        const int nb = 5120 - sb;                // idle (next) buffer
        if (e0 + 32 < Eq) {
            // write prefetched step e0+32 into the idle buffer (overlaps MFMA)
            *(bf16x8*)(lds_a + nb + wa0) = pa0; *(bf16x8*)(lds_a + nb + wa1) = pa1;
            *(bf16x8*)(lds_b + nb + wa0) = pb0; *(bf16x8*)(lds_b + nb + wa1) = pb1;
            if (e0 + 64 < Eq) {
                // issue global loads for step e0+64 (land next iteration)
                pa0 = *(const bf16x8*)(gA0 + e0 + 64);
                pa1 = *(const bf16x8*)(gA1 + e0 + 64);
                pb0 = *(const bf16x8*)(gB0 + e0 + 64);
                pb1 = *(const bf16x8*)(gB1 + e0 + 64);
            }
        }

        bf16x8 af[4], bfr[4];
#pragma unroll
        for (int i = 0; i < 4; ++i)
            af[i] = *(const bf16x8*)(lds_a + sb + (wm * 64 + i * 16 + l15) * 40 + quad * 8);
#pragma unroll
        for (int j = 0; j < 4; ++j)
            bfr[j] = *(const bf16x8*)(lds_b + sb + (wn * 64 + j * 16 + l15) * 40 + quad * 8);
#pragma unroll
        for (int i = 0; i < 4; ++i)
#pragma unroll
            for (int j = 0; j < 4; ++j)
                acc[i][j] = __builtin_amdgcn_mfma_f32_16x16x32_bf16(af[i], bfr[j], acc[i][j], 0, 0, 0);
        __syncthreads();   // step e0+32 fully staged; reads of buf sb done
    }

    const int mw = m0 + wm * 64;
    const int nw = n0 + wn * 64;
    const int h = nw >> 6;
#pragma unroll
    for (int i = 0; i < 4; ++i) {
        float ss[4] = {0.f, 0.f, 0.f, 0.f};
#pragma unroll
        for (int r = 0; r < 4; ++r) {
            int tok = mw + i * 16 + quad * 4 + r;
            int b = tok >> 11, l = tok & 2047;
#pragma unroll
            for (int j = 0; j < 4; ++j) {
                int d = (nw + j * 16 + l15) & 63;
                short sb2 = f2bf(acc[i][j][r]);
                float sv = bf2f(sb2);
                ss[r] += sv * sv;
                size_t idx = transposed
                                 ? (((size_t)(b * Hq + h) * Dq + d) * Lq + l)
                                 : (((size_t)(b * Hq + h) * Lq + l) * Dq + d);
                outb[idx] = sb2;
            }
        }
        if (x2 != nullptr) {
#pragma unroll
            for (int r = 0; r < 4; ++r) {
#pragma unroll
                for (int off = 1; off < 16; off <<= 1) ss[r] += __shfl_xor(ss[r], off);
            }
            if (l15 == 0) {
#pragma unroll
                for (int r = 0; r < 4; ++r) {
                    int tok = mw + i * 16 + quad * 4 + r;
                    int b = tok >> 11, l = tok & 2047;
                    x2[(size_t)(b * Hq + h) * Lq + l] = ss[r] * C2LOG2E;
                }
            }
        }
    }
}

// Flash attention, scores = -||q-k||, fixed softmax max = 0.  (measured-best
// 80.8us form.) S^T = K.Q^T (swapped operands): lane holds
// P[q=l15][keys quad*4..+3]. Single barrier per 64-key tile; K/V double-
// buffered in LDS (XOR-swizzled stride-64 tiles: 16K+16K+8K = 40960B =
// 4 blocks/CU). Iter i: ds_write prefetched tile i+1 -> idle buffer, issue
// global loads for tile i+2, compute tile i, ONE barrier.
// Grid (32, B*H) = 1024 blocks, 256 threads.
__global__ __launch_bounds__(256) void flash_kernel(const short* __restrict__ qb,
                                                    const short* __restrict__ kb,
                                                    const short* __restrict__ vT,
                                                    const float* __restrict__ q2,
                                                    const float* __restrict__ k2,
                                                    float* __restrict__ osum) {
    const int wave = threadIdx.x >> 6;
    const int lane = threadIdx.x & 63;
    const int l15 = lane & 15, quad = lane >> 4;
    const int bh = blockIdx.y;
    const int q0 = blockIdx.x * 64 + wave * 16;
    const short* qbh = qb + (size_t)bh * Lq * Dq;
    const short* kbh = kb + (size_t)bh * Lq * Dq;
    const short* vbh = vT + (size_t)bh * Dq * Lq;
    const float* q2h = q2 + (size_t)bh * Lq;
    const float* k2h = k2 + (size_t)bh * Lq;

    __shared__ __align__(16) short lds_k[2 * 64 * 64];   // K double buffer
    __shared__ __align__(16) short lds_v[2 * 64 * 64];   // V double buffer
    __shared__ __align__(16) short plds[4 * 16 * 64];    // P per wave (swizzled)
    short* pl = plds + wave * 1024;

    // Q fragment (B-operand of S^T): lane l15 = q-row, cols quad*8..+7
    const short* qp = qbh + (size_t)(q0 + l15) * Dq + quad * 8;
    bf16x8 qf0 = *(const bf16x8*)qp;
    bf16x8 qf1 = *(const bf16x8*)(qp + 32);
    const float q2l = q2h[q0 + l15];   // pre-scaled by C2LOG2E

    // staging geometry: thread t covers 16B chunks t and t+256 of each 8KB tile
    const int row0 = threadIdx.x >> 3;
    const int row1 = 32 + row0;
    const int sc = (threadIdx.x & 7) * 8;
    const int w0 = swz(row0 * 64 + sc);
    const int w1 = swz(row1 * 64 + sc);

    f32x4 o[4] = {};
    float lsum = 0.f;

    // prologue: tile 0 -> regs -> buf0; tile 1 -> regs
    bf16x8 kp0 = *(const bf16x8*)(kbh + (size_t)row0 * Dq + sc);
    bf16x8 kp1 = *(const bf16x8*)(kbh + (size_t)row1 * Dq + sc);
    bf16x8 vp0 = *(const bf16x8*)(vbh + (size_t)row0 * Lq + sc);
    bf16x8 vp1 = *(const bf16x8*)(vbh + (size_t)row1 * Lq + sc);
    *(bf16x8*)(lds_k + w0) = kp0; *(bf16x8*)(lds_k + w1) = kp1;
    *(bf16x8*)(lds_v + w0) = vp0; *(bf16x8*)(lds_v + w1) = vp1;
    kp0 = *(const bf16x8*)(kbh + (size_t)(64 + row0) * Dq + sc);
    kp1 = *(const bf16x8*)(kbh + (size_t)(64 + row1) * Dq + sc);
    vp0 = *(const bf16x8*)(vbh + (size_t)row0 * Lq + 64 + sc);
    vp1 = *(const bf16x8*)(vbh + (size_t)row1 * Lq + 64 + sc);
    __syncthreads();

#pragma unroll 1
    for (int it = 0; it < Lq / 64; ++it) {
        const int k0 = it * 64;
        const short* kc = lds_k + (it & 1) * 4096;
        const short* vc = lds_v + (it & 1) * 4096;
        if (it + 1 < Lq / 64) {
            // write prefetched tile it+1 into the idle buffer (overlaps compute)
            short* kn = lds_k + ((it + 1) & 1) * 4096;
            short* vn = lds_v + ((it + 1) & 1) * 4096;
            *(bf16x8*)(kn + w0) = kp0; *(bf16x8*)(kn + w1) = kp1;
            *(bf16x8*)(vn + w0) = vp0; *(bf16x8*)(vn + w1) = vp1;
            if (it + 2 < Lq / 64) {
                // issue global loads for tile it+2 (land next iteration)
                const short* ks = kbh + (size_t)(k0 + 128) * Dq;
                kp0 = *(const bf16x8*)(ks + (size_t)row0 * Dq + sc);
                kp1 = *(const bf16x8*)(ks + (size_t)row1 * Dq + sc);
                vp0 = *(const bf16x8*)(vbh + (size_t)row0 * Lq + k0 + 128 + sc);
                vp1 = *(const bf16x8*)(vbh + (size_t)row1 * Lq + k0 + 128 + sc);
            }
        }

        // scores: S^T = K.Q^T; lane -> P[q=l15][key=kt*16+quad*4+r]
#pragma unroll
        for (int kt = 0; kt < 4; ++kt) {
            bf16x8 kf0 = *(const bf16x8*)(kc + swz((kt * 16 + l15) * 64 + quad * 8));
            bf16x8 kf1 = *(const bf16x8*)(kc + swz((kt * 16 + l15) * 64 + 32 + quad * 8));
            f32x4 st = {0.f, 0.f, 0.f, 0.f};
            st = __builtin_amdgcn_mfma_f32_16x16x32_bf16(kf0, qf0, st, 0, 0, 0);
            st = __builtin_amdgcn_mfma_f32_16x16x32_bf16(kf1, qf1, st, 0, 0, 0);
            float4 k2v = *(const float4*)(k2h + k0 + kt * 16 + quad * 4);  // pre-scaled
            float pv[4];
#pragma unroll
            for (int r = 0; r < 4; ++r) {
                // d2' = C2*(q2+k2-2qk): fold -2*C2 into the fmaf constant
                float d2 = fmaxf(fmaf(st[r], NEG2C2, q2l + ((const float*)&k2v)[r]), 0.f);
                float ys = __builtin_amdgcn_sqrtf(d2);
                pv[r] = __builtin_amdgcn_exp2f(-ys);   // neg folds into v_exp src mod
            }
            lsum += (pv[0] + pv[1]) + (pv[2] + pv[3]);
            // pack 4 bf16 with 2x v_cvt_pk_bf16_f32 (no builtin on gfx950)
            unsigned plo, phi;
            asm("v_cvt_pk_bf16_f32 %0, %1, %2" : "=v"(plo) : "v"(pv[0]), "v"(pv[1]));
            asm("v_cvt_pk_bf16_f32 %0, %1, %2" : "=v"(phi) : "v"(pv[2]), "v"(pv[3]));
            uint2 pw; pw.x = plo; pw.y = phi;
            // packed b64 write: row q=l15, cols kt*16+quad*4..+3
            *(uint2*)(pl + swz(l15 * 64 + kt * 16 + quad * 4)) = pw;
        }
        // PV: P back as K=32 A-fragment (b128), V as B-fragment (b128)
#pragma unroll
        for (int kc2 = 0; kc2 < 2; ++kc2) {
            bf16x8 pa = *(const bf16x8*)(pl + swz(l15 * 64 + kc2 * 32 + quad * 8));
#pragma unroll
            for (int f = 0; f < 4; ++f) {
                bf16x8 vf = *(const bf16x8*)(vc + swz((f * 16 + l15) * 64 + kc2 * 32 + quad * 8));
                o[f] = __builtin_amdgcn_mfma_f32_16x16x32_bf16(pa, vf, o[f], 0, 0, 0);
            }
        }
        __syncthreads();   // tile it+1 fully staged; reads of buf (it&1) done
    }

    // lsum: lane holds partial for q-row l15 (its quad's keys); reduce over quads
    lsum += __shfl_xor(lsum, 16);
    lsum += __shfl_xor(lsum, 32);
    // O lane layout: row=quad*4+r = q-row, col=l15 = d-within-16
    float lq[4];
#pragma unroll
    for (int r = 0; r < 4; ++r) lq[r] = __shfl(lsum, quad * 4 + r);
#pragma unroll
    for (int f = 0; f < 4; ++f) {
        float cs = o[f][0] / lq[0] + o[f][1] / lq[1] +
                   o[f][2] / lq[2] + o[f][3] / lq[3];
        cs += __shfl_xor(cs, 16);
        cs += __shfl_xor(cs, 32);
        if (quad == 0) atomicAdd(&osum[(size_t)bh * Dq + f * 16 + l15], cs);
    }
}

// out[b,j] = sum_e osum[b,e] * Wo[j,e]; one wave per output element
__global__ __launch_bounds__(256) void outproj_kernel(const float* __restrict__ osum,
                                                      const float* __restrict__ Wo,
                                                      float* __restrict__ out) {
    int idx = blockIdx.x * 4 + (threadIdx.x >> 6);
    int lane = threadIdx.x & 63;
    int b = idx >> 10, j = idx & 1023;
    const float* o = osum + (size_t)b * Eq;
    const float* w = Wo + (size_t)j * Eq;
    float4 s4 = {0.f, 0.f, 0.f, 0.f};
    for (int e = lane * 4; e < Eq; e += 256) {
        float4 ov = *(const float4*)(o + e);
        float4 wv = *(const float4*)(w + e);
        s4.x += ov.x * wv.x; s4.y += ov.y * wv.y;
        s4.z += ov.z * wv.z; s4.w += ov.w * wv.w;
    }
    float s = s4.x + s4.y + s4.z + s4.w;
#pragma unroll
    for (int off = 1; off < 64; off <<= 1) s += __shfl_xor(s, off);
    if (lane == 0) out[idx] = s;
}

extern "C" void kernel_launch(void* const* d_in, const int* in_sizes, int n_in,
                              void* d_out, int out_size, void* d_ws, size_t ws_size,
                              hipStream_t stream) {
    const float* Q  = (const float*)d_in[0];
    const float* K  = (const float*)d_in[1];
    const float* V  = (const float*)d_in[2];
    const float* Wq = (const float*)d_in[3];
    const float* Wk = (const float*)d_in[4];
    const float* Wv = (const float*)d_in[5];
    const float* Wo = (const float*)d_in[6];
    float* out = (float*)d_out;

    char* ws = (char*)d_ws;
    // [0,8M) qb | [8M,16M) kb | [16M,24M) vT | q2 | k2 | osum | [25M,55M) castb
    short* qb = (short*)ws;
    short* kb = (short*)(ws + (size_t)(8 << 20));
    short* vT = (short*)(ws + (size_t)(16 << 20));
    float* q2 = (float*)(ws + (size_t)(24 << 20));
    float* k2 = (float*)(ws + (size_t)(24 << 20) + (256 << 10));
    float* os = (float*)(ws + (size_t)(24 << 20) + (512 << 10));
    short* castb = (short*)(ws + (size_t)(25 << 20));

    cast_all<<<15362, 256, 0, stream>>>(Q, K, V, Wq, Wk, Wv, castb, os);
    proj3_kernel<<<dim3(32, 24), 256, 0, stream>>>(castb, qb, kb, vT, q2, k2);
    flash_kernel<<<dim3(32, 32), 256, 0, stream>>>(qb, kb, vT, q2, k2, os);
    outproj_kernel<<<512, 256, 0, stream>>>(os, Wo, out);
}